// Round 4
// baseline (76.706 us; speedup 1.0000x reference)
//
#include <hip/hip_runtime.h>
#include <math.h>

#define BLK 256
#define NPTS 4096
#define XT 32             // x-tiles of 128 per (dir, b)

using short8 = __attribute__((ext_vector_type(8))) short;
using f32x16 = __attribute__((ext_vector_type(16))) float;

// Completion counter for the fused last-block-done reduction. Zero-initialized
// at module load; the last block resets it to 0 after use, so every
// launch/graph-replay starts from 0.
__device__ int g_cnt = 0;

// bf16 RNE helpers (no NaN concern for this data).
__device__ inline unsigned short f2bf(float f) {
  unsigned u = __float_as_uint(f);
  return (unsigned short)((u + 0x7FFFu + ((u >> 16) & 1u)) >> 16);
}
__device__ inline float bf2f(unsigned short h) {
  return __uint_as_float((unsigned)h << 16);
}
__device__ inline unsigned pk(unsigned short lo, unsigned short hi) {
  return (unsigned)lo | ((unsigned)hi << 16);
}

// MFMA chamfer, 32x32x16, single-dispatch. dist = (-2x.y + y^2)_MFMA + x^2_f32.
// K=16 slot map (A = y-record row, B = x col):
//   k0-2: yh_i * -2xh_i   k3-5: yl_i * -2xh_i
//   k6-8: yh_i * -2xl_i   k9-11: yl_i * -2xl_i
//   k12-14: y2h,y2m,y2l * 1.0   k15: 0
// 32x32x16 A-frag: lanes 0-31 hold k0-7 (record word0), lanes 32-63 k8-15
// (word1) -> each ds_read_b128 is fully distinct bytes.
//
// R2->R3 history: 16x16 version was DS-pipe-bound (4 waves re-reading all
// records); this wave-owns-y-slice 32x32 layout cut DS 8x -> kernel ~4us,
// VALU/DS/MFMA all near floor (~2/2/0.9us, overlapped).
//
// R4 change: fuse the final combine (old 2nd dispatch) via last-block-done.
// Block writes its partial with an agent-scope release store (writes through
// the non-coherent per-XCD L2s), acq_rel-increments g_cnt; the block seeing
// 511 acquire-loads all 512 partials and reproduces the old final kernel's
// EXACT reduction tree (dir0/dir1 butterflied separately over 32-lane
// groups, then added, then scaled) -> bitwise-identical result, one fewer
// dispatch (~2us kernel + launch gap).
//
// Harness context: ~40us of the window is the 256MiB ws re-poison
// (fillBufferAligned rows); the rest beyond the kernels is launch/graph
// overhead - the only controllable piece was dispatch count.
__global__ __launch_bounds__(BLK, 2) void chamfer_mfma_kernel(
    const float* __restrict__ X, const float* __restrict__ Y,
    float* __restrict__ sums, float* __restrict__ out)
{
  __shared__ uint4 rec[4096];   // [2][2048] SoA record words, 64 KiB
  __shared__ float gred0[8], gred1[8];
  __shared__ int lastFlag;

  int bid = blockIdx.x;
  int xt  = bid & 31;
  int b   = (bid >> 5) & 7;
  int dir = bid >> 8;

  const float* xs = (dir ? Y : X) + b * (NPTS * 3);
  const float* ys = (dir ? X : Y) + b * (NPTS * 3);

  int t = threadIdx.x;
  int lane = t & 63;
  int w = t >> 6;
  int half = lane >> 5;  // 0: k0-7 (word0), 1: k8-15 (word1)
  int c = lane & 31;     // x col within 32-col group

  // ---- B-frags: 4 x-groups of 32 cols, fixed for the whole kernel ----
  const unsigned short ONE = 0x3F80;
  short8 bf[4];
  #pragma unroll
  for (int xg = 0; xg < 4; ++xg) {
    const float* xp = xs + (xt * 128 + xg * 32 + c) * 3;
    float x0 = xp[0], x1 = xp[1], x2c = xp[2];
    unsigned short h0 = f2bf(x0), h1 = f2bf(x1), h2 = f2bf(x2c);
    unsigned short l0 = f2bf(x0 - bf2f(h0));
    unsigned short l1 = f2bf(x1 - bf2f(h1));
    unsigned short l2 = f2bf(x2c - bf2f(h2));
    unsigned short mh0 = f2bf(-2.0f * bf2f(h0));
    unsigned short mh1 = f2bf(-2.0f * bf2f(h1));
    unsigned short mh2 = f2bf(-2.0f * bf2f(h2));
    unsigned short ml0 = f2bf(-2.0f * bf2f(l0));
    unsigned short ml1 = f2bf(-2.0f * bf2f(l1));
    unsigned short ml2 = f2bf(-2.0f * bf2f(l2));
    short8 v;
    if (half == 0) {
      v[0] = mh0; v[1] = mh1; v[2] = mh2; v[3] = mh0;
      v[4] = mh1; v[5] = mh2; v[6] = ml0; v[7] = ml1;
    } else {
      v[0] = ml2; v[1] = ml0; v[2] = ml1; v[3] = ml2;
      v[4] = ONE; v[5] = ONE; v[6] = ONE; v[7] = 0;
    }
    bf[xg] = v;
  }

  float gm[4];
  #pragma unroll
  for (int xg = 0; xg < 4; ++xg) gm[xg] = __builtin_inff();
  f32x16 cz = {0.0f, 0.0f, 0.0f, 0.0f, 0.0f, 0.0f, 0.0f, 0.0f,
               0.0f, 0.0f, 0.0f, 0.0f, 0.0f, 0.0f, 0.0f, 0.0f};
  const short8* recp = reinterpret_cast<const short8*>(rec);
  int abase = half * 2048 + w * 512 + c;   // wave owns records [w*512, +512)

  for (int p = 0; p < 2; ++p) {
    // ---- stage 2048 y-records (SoA: word0 region, then word1 region) ----
    #pragma unroll
    for (int i = 0; i < 8; ++i) {
      int yl_ = t + i * 256;
      const float* yp = ys + (p * 2048 + yl_) * 3;
      float y0 = yp[0], y1 = yp[1], y2c = yp[2];
      unsigned short h0 = f2bf(y0), h1 = f2bf(y1), h2 = f2bf(y2c);
      unsigned short l0 = f2bf(y0 - bf2f(h0));
      unsigned short l1 = f2bf(y1 - bf2f(h1));
      unsigned short l2 = f2bf(y2c - bf2f(h2));
      float ysq = fmaf(y0, y0, fmaf(y1, y1, y2c * y2c));
      unsigned short s0 = f2bf(ysq);
      float r1 = ysq - bf2f(s0);
      unsigned short s1 = f2bf(r1);
      unsigned short s2 = f2bf(r1 - bf2f(s1));
      uint4 w0, w1;
      w0.x = pk(h0, h1); w0.y = pk(h2, l0); w0.z = pk(l1, l2); w0.w = pk(h0, h1);
      w1.x = pk(h2, l0); w1.y = pk(l1, l2); w1.z = pk(s0, s1); w1.w = pk(s2, 0);
      rec[yl_] = w0;
      rec[2048 + yl_] = w1;
    }
    __syncthreads();

    // ---- wave's 16 y-tiles of 32: 1 ds_read_b128 + 4 MFMA + 32 v_min3 ----
    #pragma unroll 4
    for (int tile = 0; tile < 16; ++tile) {
      short8 a = recp[abase + tile * 32];
      #pragma unroll
      for (int xg = 0; xg < 4; ++xg) {
        f32x16 d =
            __builtin_amdgcn_mfma_f32_32x32x16_bf16(a, bf[xg], cz, 0, 0, 0);
        float m0 = fminf(fminf(d[0], d[1]), d[2]);
        float m1 = fminf(fminf(d[3], d[4]), d[5]);
        float m2 = fminf(fminf(d[6], d[7]), d[8]);
        float m3 = fminf(fminf(d[9], d[10]), d[11]);
        float m4 = fminf(fminf(d[12], d[13]), d[14]);
        float n0 = fminf(fminf(m0, m1), m2);
        float n1 = fminf(fminf(m3, m4), d[15]);
        gm[xg] = fminf(fminf(n0, n1), gm[xg]);
      }
    }
    __syncthreads();
  }

  // ---- combine: lane halves, then cross-wave via 2KB LDS partials ----
  #pragma unroll
  for (int xg = 0; xg < 4; ++xg)
    gm[xg] = fminf(gm[xg], __shfl_xor(gm[xg], 32, 64));

  float* pf = reinterpret_cast<float*>(rec);   // safe after last sync
  if (lane < 32) {
    #pragma unroll
    for (int xg = 0; xg < 4; ++xg) pf[w * 128 + xg * 32 + c] = gm[xg];
  }
  __syncthreads();

  float v = 0.0f;
  if (t < 128) {   // waves 0,1: one x-point each
    float m = fminf(fminf(pf[t], pf[128 + t]), fminf(pf[256 + t], pf[384 + t]));
    const float* xp = xs + (xt * 128 + t) * 3;
    float a0 = xp[0], a1 = xp[1], a2 = xp[2];
    v = m + fmaf(a0, a0, fmaf(a1, a1, a2 * a2));
  }
  #pragma unroll
  for (int mm = 1; mm < 64; mm <<= 1) v += __shfl_xor(v, mm, 64);
  if (lane == 0 && t < 128) pf[512 + w] = v;   // distinct region, no hazard
  __syncthreads();

  // ---- publish partial + last-block-done final combine ----
  if (t == 0) {
    float bs = pf[512] + pf[513];
    __hip_atomic_store(&sums[bid], bs, __ATOMIC_RELEASE,
                       __HIP_MEMORY_SCOPE_AGENT);
    int old = __hip_atomic_fetch_add(&g_cnt, 1, __ATOMIC_ACQ_REL,
                                     __HIP_MEMORY_SCOPE_AGENT);
    lastFlag = (old == 511);
  }
  __syncthreads();
  if (!lastFlag) return;

  // Last block: replicate the old final kernel's exact tree. Thread t
  // handles sums[t] (dir0) and sums[t+256] (dir1); butterfly each over its
  // 32-lane group (masks 1..16 stay in-group), add group results, scale.
  float v0 = __hip_atomic_load(&sums[t], __ATOMIC_ACQUIRE,
                               __HIP_MEMORY_SCOPE_AGENT);
  float v1 = __hip_atomic_load(&sums[t + 256], __ATOMIC_ACQUIRE,
                               __HIP_MEMORY_SCOPE_AGENT);
  #pragma unroll
  for (int mm = 1; mm < 32; mm <<= 1) {
    v0 += __shfl_xor(v0, mm, 64);
    v1 += __shfl_xor(v1, mm, 64);
  }
  if ((t & 31) == 0) {     // group leader: group = b = t>>5
    gred0[t >> 5] = v0;
    gred1[t >> 5] = v1;
  }
  __syncthreads();
  if (t < 8) out[t] = (gred0[t] + gred1[t]) * (1.0f / 4096.0f);
  if (t == 0)
    __hip_atomic_store(&g_cnt, 0, __ATOMIC_RELEASE, __HIP_MEMORY_SCOPE_AGENT);
}

// Fallback (workspace too small): exact-fp32 full-range direct kernel.
__global__ __launch_bounds__(BLK, 2) void chamfer_direct_kernel(
    const float* __restrict__ X, const float* __restrict__ Y,
    float* __restrict__ out)
{
  extern __shared__ float4 shd[];
  int lin = blockIdx.x;
  int xt  = lin & 1;  lin >>= 1;
  int b   = lin & 7;
  int dir = lin >> 3;
  const float* xs = (dir ? Y : X) + b * (NPTS * 3);
  const float* ys = (dir ? X : Y) + b * (NPTS * 3);

  for (int j = threadIdx.x; j < NPTS; j += BLK) {
    float y0 = ys[j * 3 + 0], y1 = ys[j * 3 + 1], y2 = ys[j * 3 + 2];
    shd[j] = make_float4(y0, y1, y2, 0.5f * (y0 * y0 + y1 * y1 + y2 * y2));
  }
  __syncthreads();

  int x0i = xt * (BLK * 8) + threadIdx.x * 8;
  float xf[24];
  const float4* xp = reinterpret_cast<const float4*>(xs + x0i * 3);
  #pragma unroll
  for (int i = 0; i < 6; ++i) {
    float4 p = xp[i];
    xf[i * 4 + 0] = p.x; xf[i * 4 + 1] = p.y;
    xf[i * 4 + 2] = p.z; xf[i * 4 + 3] = p.w;
  }
  float n0[8], n1[8], n2[8], x2h[8], gm[8];
  #pragma unroll
  for (int k = 0; k < 8; ++k) {
    float a = xf[k * 3 + 0], bb = xf[k * 3 + 1], cc = xf[k * 3 + 2];
    n0[k] = -a; n1[k] = -bb; n2[k] = -cc;
    x2h[k] = 0.5f * (a * a + bb * bb + cc * cc);
    gm[k] = __builtin_inff();
  }
  for (int j = 0; j < NPTS; j += 4) {
    float4 p0 = shd[j], p1 = shd[j + 1], p2 = shd[j + 2], p3 = shd[j + 3];
    #pragma unroll
    for (int k = 0; k < 8; ++k) {
      float ga = fmaf(n0[k], p0.x, fmaf(n1[k], p0.y, fmaf(n2[k], p0.z, p0.w)));
      float gb = fmaf(n0[k], p1.x, fmaf(n1[k], p1.y, fmaf(n2[k], p1.z, p1.w)));
      float gc = fmaf(n0[k], p2.x, fmaf(n1[k], p2.y, fmaf(n2[k], p2.z, p2.w)));
      float gd = fmaf(n0[k], p3.x, fmaf(n1[k], p3.y, fmaf(n2[k], p3.z, p3.w)));
      float m  = fminf(fminf(ga, gb), gc);
      gm[k] = fminf(fminf(m, gd), gm[k]);
    }
  }
  float v = 0.0f;
  #pragma unroll
  for (int k = 0; k < 8; ++k) v += 2.0f * (x2h[k] + gm[k]);
  #pragma unroll
  for (int off = 32; off > 0; off >>= 1) v += __shfl_down(v, off, 64);
  __syncthreads();
  float* red = reinterpret_cast<float*>(shd);
  if ((threadIdx.x & 63) == 0) red[threadIdx.x >> 6] = v;
  __syncthreads();
  if (threadIdx.x == 0) {
    float s2 = red[0] + red[1] + red[2] + red[3];
    atomicAdd(&out[b], s2 * (1.0f / 4096.0f));
  }
}

__global__ void zero_out_kernel(float* out)
{
  if (threadIdx.x < 8) out[threadIdx.x] = 0.0f;
}

extern "C" void kernel_launch(void* const* d_in, const int* in_sizes, int n_in,
                              void* d_out, int out_size, void* d_ws, size_t ws_size,
                              hipStream_t stream)
{
  const float* X = (const float*)d_in[0];
  const float* Y = (const float*)d_in[1];
  float* out = (float*)d_out;

  if (ws_size >= (size_t)(2 * 8 * XT) * sizeof(float)) {
    // 512 blocks = 2 dirs * 8 batches * 32 x-tiles; 2 blocks/CU; single
    // dispatch (last-block-done final combine).
    chamfer_mfma_kernel<<<2 * 8 * XT, BLK, 0, stream>>>(X, Y, (float*)d_ws,
                                                        out);
  } else {
    zero_out_kernel<<<1, 64, 0, stream>>>(out);
    chamfer_direct_kernel<<<2 * 8 * 2, BLK, NPTS * sizeof(float4), stream>>>(
        X, Y, out);
  }
}

// Round 5
// 69.229 us; speedup vs baseline: 1.1080x; 1.1080x over previous
//
#include <hip/hip_runtime.h>
#include <math.h>

#define BLK 256
#define NPTS 4096
#define XT 32             // x-tiles of 128 per (dir, b)

using short8 = __attribute__((ext_vector_type(8))) short;
using f32x16 = __attribute__((ext_vector_type(16))) float;

// bf16 RNE helpers (no NaN concern for this data).
__device__ inline unsigned short f2bf(float f) {
  unsigned u = __float_as_uint(f);
  return (unsigned short)((u + 0x7FFFu + ((u >> 16) & 1u)) >> 16);
}
__device__ inline float bf2f(unsigned short h) {
  return __uint_as_float((unsigned)h << 16);
}
__device__ inline unsigned pk(unsigned short lo, unsigned short hi) {
  return (unsigned)lo | ((unsigned)hi << 16);
}

// MFMA chamfer, 32x32x16 variant. Math: dist = (-2x.y + y^2)_MFMA + x^2_f32.
// K=16 slot map (A = y-record row, B = x col):
//   k0-2: yh_i * -2xh_i   k3-5: yl_i * -2xh_i
//   k6-8: yh_i * -2xl_i   k9-11: yl_i * -2xl_i
//   k12-14: y2h,y2m,y2l * 1.0   k15: 0
// 32x32x16 A-frag layout: lanes 0-31 hold k0-7 (record word0), lanes 32-63
// k8-15 (word1) -> each ds_read_b128 is fully distinct bytes.
//
// Session ledger (do not retry):
//  - R2: 16x16 version was DS-pipe-bound (4 waves re-read all records).
//  - R3 (this kernel): wave-owns-y-slice, 32x32, DS cut 8x -> 67.1us total;
//    kernel ~4us with VALU/DS/MFMA at ~2.2/1.9/0.85us (overlapped) - all
//    pipes near floor.
//  - R4 FAILED (+9.6us): last-block-done fusion via agent-scope release
//    store + acq_rel counter. Per-XCD L2s are non-coherent, so every
//    block's agent-scope release/RMW forces cache maintenance (~10us over
//    512 blocks). Two-dispatch stream ordering IS the cheap sync on this
//    chip (same lesson as grid.sync=+50us, atomicMin write-through=never).
//
// Harness context: ~40us of the window is the 256MiB ws re-poison
// (fillBufferAligned rows); ~21us is fixed graph/launch overhead (constant
// across rounds, NOT per-dispatch-reclaimable per R4) - neither is
// controllable from kernel code. Controllable floor ~= 5.5us of kernels.
__global__ __launch_bounds__(BLK, 2) void chamfer_mfma_kernel(
    const float* __restrict__ X, const float* __restrict__ Y,
    float* __restrict__ sums)
{
  __shared__ uint4 rec[4096];   // [2][2048] SoA record words, 64 KiB

  int bid = blockIdx.x;
  int xt  = bid & 31;
  int b   = (bid >> 5) & 7;
  int dir = bid >> 8;

  const float* xs = (dir ? Y : X) + b * (NPTS * 3);
  const float* ys = (dir ? X : Y) + b * (NPTS * 3);

  int t = threadIdx.x;
  int lane = t & 63;
  int w = t >> 6;
  int half = lane >> 5;  // 0: k0-7 (word0), 1: k8-15 (word1)
  int c = lane & 31;     // x col within 32-col group

  // ---- B-frags: 4 x-groups of 32 cols, fixed for the whole kernel ----
  const unsigned short ONE = 0x3F80;
  short8 bf[4];
  #pragma unroll
  for (int xg = 0; xg < 4; ++xg) {
    const float* xp = xs + (xt * 128 + xg * 32 + c) * 3;
    float x0 = xp[0], x1 = xp[1], x2c = xp[2];
    unsigned short h0 = f2bf(x0), h1 = f2bf(x1), h2 = f2bf(x2c);
    unsigned short l0 = f2bf(x0 - bf2f(h0));
    unsigned short l1 = f2bf(x1 - bf2f(h1));
    unsigned short l2 = f2bf(x2c - bf2f(h2));
    unsigned short mh0 = f2bf(-2.0f * bf2f(h0));
    unsigned short mh1 = f2bf(-2.0f * bf2f(h1));
    unsigned short mh2 = f2bf(-2.0f * bf2f(h2));
    unsigned short ml0 = f2bf(-2.0f * bf2f(l0));
    unsigned short ml1 = f2bf(-2.0f * bf2f(l1));
    unsigned short ml2 = f2bf(-2.0f * bf2f(l2));
    short8 v;
    if (half == 0) {
      v[0] = mh0; v[1] = mh1; v[2] = mh2; v[3] = mh0;
      v[4] = mh1; v[5] = mh2; v[6] = ml0; v[7] = ml1;
    } else {
      v[0] = ml2; v[1] = ml0; v[2] = ml1; v[3] = ml2;
      v[4] = ONE; v[5] = ONE; v[6] = ONE; v[7] = 0;
    }
    bf[xg] = v;
  }

  float gm[4];
  #pragma unroll
  for (int xg = 0; xg < 4; ++xg) gm[xg] = __builtin_inff();
  f32x16 cz = {0.0f, 0.0f, 0.0f, 0.0f, 0.0f, 0.0f, 0.0f, 0.0f,
               0.0f, 0.0f, 0.0f, 0.0f, 0.0f, 0.0f, 0.0f, 0.0f};
  const short8* recp = reinterpret_cast<const short8*>(rec);
  int abase = half * 2048 + w * 512 + c;   // wave owns records [w*512, +512)

  for (int p = 0; p < 2; ++p) {
    // ---- stage 2048 y-records (SoA: word0 region, then word1 region) ----
    #pragma unroll
    for (int i = 0; i < 8; ++i) {
      int yl_ = t + i * 256;
      const float* yp = ys + (p * 2048 + yl_) * 3;
      float y0 = yp[0], y1 = yp[1], y2c = yp[2];
      unsigned short h0 = f2bf(y0), h1 = f2bf(y1), h2 = f2bf(y2c);
      unsigned short l0 = f2bf(y0 - bf2f(h0));
      unsigned short l1 = f2bf(y1 - bf2f(h1));
      unsigned short l2 = f2bf(y2c - bf2f(h2));
      float ysq = fmaf(y0, y0, fmaf(y1, y1, y2c * y2c));
      unsigned short s0 = f2bf(ysq);
      float r1 = ysq - bf2f(s0);
      unsigned short s1 = f2bf(r1);
      unsigned short s2 = f2bf(r1 - bf2f(s1));
      uint4 w0, w1;
      w0.x = pk(h0, h1); w0.y = pk(h2, l0); w0.z = pk(l1, l2); w0.w = pk(h0, h1);
      w1.x = pk(h2, l0); w1.y = pk(l1, l2); w1.z = pk(s0, s1); w1.w = pk(s2, 0);
      rec[yl_] = w0;
      rec[2048 + yl_] = w1;
    }
    __syncthreads();

    // ---- wave's 16 y-tiles of 32: 1 ds_read_b128 + 4 MFMA + 32 v_min3 ----
    #pragma unroll 4
    for (int tile = 0; tile < 16; ++tile) {
      short8 a = recp[abase + tile * 32];
      #pragma unroll
      for (int xg = 0; xg < 4; ++xg) {
        f32x16 d =
            __builtin_amdgcn_mfma_f32_32x32x16_bf16(a, bf[xg], cz, 0, 0, 0);
        float m0 = fminf(fminf(d[0], d[1]), d[2]);
        float m1 = fminf(fminf(d[3], d[4]), d[5]);
        float m2 = fminf(fminf(d[6], d[7]), d[8]);
        float m3 = fminf(fminf(d[9], d[10]), d[11]);
        float m4 = fminf(fminf(d[12], d[13]), d[14]);
        float n0 = fminf(fminf(m0, m1), m2);
        float n1 = fminf(fminf(m3, m4), d[15]);
        gm[xg] = fminf(fminf(n0, n1), gm[xg]);
      }
    }
    __syncthreads();
  }

  // ---- combine: lane halves, then cross-wave via 2KB LDS partials ----
  #pragma unroll
  for (int xg = 0; xg < 4; ++xg)
    gm[xg] = fminf(gm[xg], __shfl_xor(gm[xg], 32, 64));

  float* pf = reinterpret_cast<float*>(rec);   // safe after last sync
  if (lane < 32) {
    #pragma unroll
    for (int xg = 0; xg < 4; ++xg) pf[w * 128 + xg * 32 + c] = gm[xg];
  }
  __syncthreads();

  float v = 0.0f;
  if (t < 128) {   // waves 0,1: one x-point each
    float m = fminf(fminf(pf[t], pf[128 + t]), fminf(pf[256 + t], pf[384 + t]));
    const float* xp = xs + (xt * 128 + t) * 3;
    float a0 = xp[0], a1 = xp[1], a2 = xp[2];
    v = m + fmaf(a0, a0, fmaf(a1, a1, a2 * a2));
  }
  #pragma unroll
  for (int mm = 1; mm < 64; mm <<= 1) v += __shfl_xor(v, mm, 64);
  if (lane == 0 && t < 128) pf[512 + w] = v;   // distinct region, no hazard
  __syncthreads();
  if (t == 0) sums[bid] = pf[512] + pf[513];
}

// Final combine: 512 block sums (L2-hot) into out[8]; single writer per
// batch, no atomics, no pre-zero. sums[bid], bid = (dir*8+b)*32 + xt.
__global__ __launch_bounds__(512) void chamfer_final_kernel(
    const float* __restrict__ sums, float* __restrict__ out)
{
  __shared__ float gred[16];
  int t = threadIdx.x;
  float v = sums[t];
  #pragma unroll
  for (int mm = 1; mm < 32; mm <<= 1) v += __shfl_xor(v, mm, 64);
  if ((t & 31) == 0) gred[t >> 5] = v;   // group = dir*8 + b
  __syncthreads();
  if (t < 8) out[t] = (gred[t] + gred[t + 8]) * (1.0f / 4096.0f);
}

// Fallback (workspace too small): exact-fp32 full-range direct kernel.
__global__ __launch_bounds__(BLK, 2) void chamfer_direct_kernel(
    const float* __restrict__ X, const float* __restrict__ Y,
    float* __restrict__ out)
{
  extern __shared__ float4 shd[];
  int lin = blockIdx.x;
  int xt  = lin & 1;  lin >>= 1;
  int b   = lin & 7;
  int dir = lin >> 3;
  const float* xs = (dir ? Y : X) + b * (NPTS * 3);
  const float* ys = (dir ? X : Y) + b * (NPTS * 3);

  for (int j = threadIdx.x; j < NPTS; j += BLK) {
    float y0 = ys[j * 3 + 0], y1 = ys[j * 3 + 1], y2 = ys[j * 3 + 2];
    shd[j] = make_float4(y0, y1, y2, 0.5f * (y0 * y0 + y1 * y1 + y2 * y2));
  }
  __syncthreads();

  int x0i = xt * (BLK * 8) + threadIdx.x * 8;
  float xf[24];
  const float4* xp = reinterpret_cast<const float4*>(xs + x0i * 3);
  #pragma unroll
  for (int i = 0; i < 6; ++i) {
    float4 p = xp[i];
    xf[i * 4 + 0] = p.x; xf[i * 4 + 1] = p.y;
    xf[i * 4 + 2] = p.z; xf[i * 4 + 3] = p.w;
  }
  float n0[8], n1[8], n2[8], x2h[8], gm[8];
  #pragma unroll
  for (int k = 0; k < 8; ++k) {
    float a = xf[k * 3 + 0], bb = xf[k * 3 + 1], cc = xf[k * 3 + 2];
    n0[k] = -a; n1[k] = -bb; n2[k] = -cc;
    x2h[k] = 0.5f * (a * a + bb * bb + cc * cc);
    gm[k] = __builtin_inff();
  }
  for (int j = 0; j < NPTS; j += 4) {
    float4 p0 = shd[j], p1 = shd[j + 1], p2 = shd[j + 2], p3 = shd[j + 3];
    #pragma unroll
    for (int k = 0; k < 8; ++k) {
      float ga = fmaf(n0[k], p0.x, fmaf(n1[k], p0.y, fmaf(n2[k], p0.z, p0.w)));
      float gb = fmaf(n0[k], p1.x, fmaf(n1[k], p1.y, fmaf(n2[k], p1.z, p1.w)));
      float gc = fmaf(n0[k], p2.x, fmaf(n1[k], p2.y, fmaf(n2[k], p2.z, p2.w)));
      float gd = fmaf(n0[k], p3.x, fmaf(n1[k], p3.y, fmaf(n2[k], p3.z, p3.w)));
      float m  = fminf(fminf(ga, gb), gc);
      gm[k] = fminf(fminf(m, gd), gm[k]);
    }
  }
  float v = 0.0f;
  #pragma unroll
  for (int k = 0; k < 8; ++k) v += 2.0f * (x2h[k] + gm[k]);
  #pragma unroll
  for (int off = 32; off > 0; off >>= 1) v += __shfl_down(v, off, 64);
  __syncthreads();
  float* red = reinterpret_cast<float*>(shd);
  if ((threadIdx.x & 63) == 0) red[threadIdx.x >> 6] = v;
  __syncthreads();
  if (threadIdx.x == 0) {
    float s2 = red[0] + red[1] + red[2] + red[3];
    atomicAdd(&out[b], s2 * (1.0f / 4096.0f));
  }
}

__global__ void zero_out_kernel(float* out)
{
  if (threadIdx.x < 8) out[threadIdx.x] = 0.0f;
}

extern "C" void kernel_launch(void* const* d_in, const int* in_sizes, int n_in,
                              void* d_out, int out_size, void* d_ws, size_t ws_size,
                              hipStream_t stream)
{
  const float* X = (const float*)d_in[0];
  const float* Y = (const float*)d_in[1];
  float* out = (float*)d_out;

  if (ws_size >= (size_t)(2 * 8 * XT) * sizeof(float)) {
    // 512 blocks = 2 dirs * 8 batches * 32 x-tiles; 2 blocks/CU (64 KiB LDS).
    chamfer_mfma_kernel<<<2 * 8 * XT, BLK, 0, stream>>>(X, Y, (float*)d_ws);
    chamfer_final_kernel<<<1, 512, 0, stream>>>((const float*)d_ws, out);
  } else {
    zero_out_kernel<<<1, 64, 0, stream>>>(out);
    chamfer_direct_kernel<<<2 * 8 * 2, BLK, NPTS * sizeof(float4), stream>>>(
        X, Y, out);
  }
}